// Round 2
// baseline (102.353 us; speedup 1.0000x reference)
//
#include <hip/hip_runtime.h>
#include <math.h>

// Problem constants (fixed by the reference).
#define BB 4
#define SS 2048
#define DD 16
#define HH 16
#define BHS (BB * HH * SS)  // 131072 elements per Q/K/V plane

#if defined(__has_builtin)
#if __has_builtin(__builtin_amdgcn_exp2f)
#define EXP2(x) __builtin_amdgcn_exp2f(x)
#else
#define EXP2(x) exp2f(x)
#endif
#else
#define EXP2(x) exp2f(x)
#endif

#define LOG2E 1.44269504088896340736f

// ---------------------------------------------------------------------------
// Kernel A: qkv = x @ w_qkv + b_qkv -> Q/K/V[b][h][s] (transposed).
// One thread per (row, h): 512 blocks x 256 threads. Block = 16 rows x 16 h.
// Weights staged transposed+padded in LDS for b128 reads (2-way bank alias
// only, which is free on gfx950).
// ---------------------------------------------------------------------------
__global__ __launch_bounds__(256) void qkv_kernel(
    const float* __restrict__ x, const float* __restrict__ w,
    const float* __restrict__ bias, float* __restrict__ Q,
    float* __restrict__ K, float* __restrict__ V) {
  __shared__ float wt[HH * 68];  // wt4[h*17 + i] = {wq, wk, wv, pad} for (h,i)
  __shared__ float xl[16 * 20];  // 16 rows x 16 cols, padded stride 20
  __shared__ float bs[3 * DD];
  const int t = threadIdx.x;

  for (int idx = t; idx < DD * 3 * DD; idx += 256) {  // 768 weight elements
    const int i = idx / 48, o = idx % 48;
    const int slot = o >> 4, h = o & 15;
    wt[h * 68 + i * 4 + slot] = w[idx];
  }
  if (t < 3 * DD) bs[t] = bias[t];
  xl[(t >> 4) * 20 + (t & 15)] = x[(size_t)blockIdx.x * 256 + t];  // coalesced
  __syncthreads();

  const int row_l = t >> 4, h = t & 15;
  const int row = blockIdx.x * 16 + row_l;  // global b*S + s
  const int b = row >> 11, s = row & (SS - 1);

  const float4* xl4 = (const float4*)xl;
  const float4* wt4 = (const float4*)wt;

  float q = bs[h], k = bs[DD + h], v = bs[2 * DD + h];
#pragma unroll
  for (int g = 0; g < 4; ++g) {
    const float4 xv = xl4[row_l * 5 + g];
    const float xs[4] = {xv.x, xv.y, xv.z, xv.w};
#pragma unroll
    for (int u = 0; u < 4; ++u) {
      const float4 wv = wt4[h * 17 + 4 * g + u];
      q = fmaf(xs[u], wv.x, q);
      k = fmaf(xs[u], wv.y, k);
      v = fmaf(xs[u], wv.z, v);
    }
  }
  const int o = (b * HH + h) * SS + s;
  Q[o] = q; K[o] = k; V[o] = v;
}

// ---------------------------------------------------------------------------
// Kernel B: causal softmax attention, head_size == 1.
// out[b,h,i] = sum_{j<=i} exp(q_i k_j) v_j / sum_{j<=i} exp(q_i k_j)
// grid = 512 blocks x 256 threads; block (c, bh), wave w covers one span of
// 64 consecutive queries. Main loop bound span*64 is wave-uniform (SGPR);
// last 64 j's are predicated. Span->wave map reverses on (blockIdx>>8)&1 so
// co-resident blocks (b, b+256) give every SIMD a span-sum of exactly 31.
// ---------------------------------------------------------------------------
__global__ __launch_bounds__(256) void attn_kernel(
    const float* __restrict__ Q, const float* __restrict__ K,
    const float* __restrict__ V, float* __restrict__ AO) {
  __shared__ float Kl[SS];
  __shared__ float Vl[SS];
  const int c = blockIdx.x & 7;
  const int bh = blockIdx.x >> 3;  // 0..63
  const int b = bh >> 4, h = bh & 15;
  const int t = threadIdx.x;

  const float4* Kg = (const float4*)(K + (size_t)bh * SS);
  const float4* Vg = (const float4*)(V + (size_t)bh * SS);
  float4* Kl4w = (float4*)Kl;
  float4* Vl4w = (float4*)Vl;
  for (int idx = t; idx < SS / 4; idx += 256) {
    Kl4w[idx] = Kg[idx];
    Vl4w[idx] = Vg[idx];
  }
  __syncthreads();

  const int wv = t >> 6, lane = t & 63;
  const int par = (blockIdx.x >> 8) & 1;
  const int ww = par ? (3 - wv) : wv;
  const int span = (ww == 0) ? c : (ww == 1) ? (15 - c)
                                 : (ww == 2) ? (16 + c) : (31 - c);
  const int i = span * 64 + lane;

  const float qs = Q[bh * SS + i] * LOG2E;  // exp(qk) = exp2(qs*k)

  const float4* Kl4 = (const float4*)Kl;
  const float4* Vl4 = (const float4*)Vl;

  float l0 = 0.f, l1 = 0.f, l2 = 0.f, l3 = 0.f;
  float a0 = 0.f, a1 = 0.f, a2 = 0.f, a3 = 0.f;

  // Main loop: wave-uniform trip count (span*16 float4 groups, %4 == 0).
  const int J4 = span * 16;
  for (int p = 0; p < J4; p += 4) {
    const float4 ka = Kl4[p + 0], kb = Kl4[p + 1];
    const float4 kc = Kl4[p + 2], kd = Kl4[p + 3];
    const float4 va = Vl4[p + 0], vb = Vl4[p + 1];
    const float4 vc = Vl4[p + 2], vd = Vl4[p + 3];
    float e;
    e = EXP2(qs * ka.x); l0 += e; a0 = fmaf(e, va.x, a0);
    e = EXP2(qs * ka.y); l1 += e; a1 = fmaf(e, va.y, a1);
    e = EXP2(qs * ka.z); l2 += e; a2 = fmaf(e, va.z, a2);
    e = EXP2(qs * ka.w); l3 += e; a3 = fmaf(e, va.w, a3);
    e = EXP2(qs * kb.x); l0 += e; a0 = fmaf(e, vb.x, a0);
    e = EXP2(qs * kb.y); l1 += e; a1 = fmaf(e, vb.y, a1);
    e = EXP2(qs * kb.z); l2 += e; a2 = fmaf(e, vb.z, a2);
    e = EXP2(qs * kb.w); l3 += e; a3 = fmaf(e, vb.w, a3);
    e = EXP2(qs * kc.x); l0 += e; a0 = fmaf(e, vc.x, a0);
    e = EXP2(qs * kc.y); l1 += e; a1 = fmaf(e, vc.y, a1);
    e = EXP2(qs * kc.z); l2 += e; a2 = fmaf(e, vc.z, a2);
    e = EXP2(qs * kc.w); l3 += e; a3 = fmaf(e, vc.w, a3);
    e = EXP2(qs * kd.x); l0 += e; a0 = fmaf(e, vd.x, a0);
    e = EXP2(qs * kd.y); l1 += e; a1 = fmaf(e, vd.y, a1);
    e = EXP2(qs * kd.z); l2 += e; a2 = fmaf(e, vd.z, a2);
    e = EXP2(qs * kd.w); l3 += e; a3 = fmaf(e, vd.w, a3);
  }

  // Tail: j = span*64 + jj, jj in [0,64); active iff jj <= lane.
#pragma unroll
  for (int g = 0; g < 16; ++g) {
    const float4 k4 = Kl4[J4 + g];
    const float4 v4 = Vl4[J4 + g];
    const int jj = 4 * g;
    float e;
    e = EXP2(qs * k4.x); e = (jj + 0 <= lane) ? e : 0.f; l0 += e; a0 = fmaf(e, v4.x, a0);
    e = EXP2(qs * k4.y); e = (jj + 1 <= lane) ? e : 0.f; l1 += e; a1 = fmaf(e, v4.y, a1);
    e = EXP2(qs * k4.z); e = (jj + 2 <= lane) ? e : 0.f; l2 += e; a2 = fmaf(e, v4.z, a2);
    e = EXP2(qs * k4.w); e = (jj + 3 <= lane) ? e : 0.f; l3 += e; a3 = fmaf(e, v4.w, a3);
  }

  const float l = (l0 + l1) + (l2 + l3);
  const float a = (a0 + a1) + (a2 + a3);
  AO[((size_t)b * SS + i) * HH + h] = a / l;  // AO layout [b][s][h]
}

// ---------------------------------------------------------------------------
// Kernel C: out = AO @ w_out + b_out. One thread per (row, d).
// 512 blocks x 256 threads; block = 16 rows x 16 d. Coalesced store.
// ---------------------------------------------------------------------------
__global__ __launch_bounds__(256) void proj_kernel(
    const float* __restrict__ AO, const float* __restrict__ w,
    const float* __restrict__ bias, float* __restrict__ out) {
  __shared__ float wct[DD * 68];  // column d at wct[d*68 + i], float4-readable
  __shared__ float xl[16 * 20];
  __shared__ float bs[DD];
  const int t = threadIdx.x;

  if (t < 256) {  // w is 16x16 = 256 elements; thread t -> (i = t>>4, d = t&15)
    wct[(t & 15) * 68 + (t >> 4)] = w[t];
  }
  if (t < DD) bs[t] = bias[t];
  xl[(t >> 4) * 20 + (t & 15)] = AO[(size_t)blockIdx.x * 256 + t];
  __syncthreads();

  const int row_l = t >> 4, d = t & 15;
  const float4* xl4 = (const float4*)xl;
  const float4* wc4 = (const float4*)wct;

  float y = bs[d];
#pragma unroll
  for (int g = 0; g < 4; ++g) {
    const float4 xv = xl4[row_l * 5 + g];
    const float4 wv = wc4[d * 17 + g];
    y = fmaf(xv.x, wv.x, y);
    y = fmaf(xv.y, wv.y, y);
    y = fmaf(xv.z, wv.z, y);
    y = fmaf(xv.w, wv.w, y);
  }
  out[(size_t)blockIdx.x * 256 + t] = y;
}

// ---------------------------------------------------------------------------
extern "C" void kernel_launch(void* const* d_in, const int* in_sizes, int n_in,
                              void* d_out, int out_size, void* d_ws,
                              size_t ws_size, hipStream_t stream) {
  const float* x = (const float*)d_in[0];       // [B,S,D]
  const float* w_qkv = (const float*)d_in[1];   // [D, 3D]
  const float* b_qkv = (const float*)d_in[2];   // [3D]
  const float* w_out = (const float*)d_in[3];   // [D, D]
  const float* b_out = (const float*)d_in[4];   // [D]
  float* out = (float*)d_out;                   // [B,S,D] fp32

  float* ws = (float*)d_ws;
  float* Q = ws;             // [B][H][S]
  float* K = ws + BHS;       // [B][H][S]
  float* V = ws + 2 * BHS;   // [B][H][S]
  float* AO = ws + 3 * BHS;  // [B][S][H]

  qkv_kernel<<<512, 256, 0, stream>>>(x, w_qkv, b_qkv, Q, K, V);
  attn_kernel<<<512, 256, 0, stream>>>(Q, K, V, AO);
  proj_kernel<<<512, 256, 0, stream>>>(AO, w_out, b_out, out);
}